// Round 9
// baseline (202.650 us; speedup 1.0000x reference)
//
#include <hip/hip_runtime.h>
#include <hip/hip_bf16.h>

typedef __attribute__((ext_vector_type(8))) short short8;
typedef __attribute__((ext_vector_type(4))) short short4v;
typedef __attribute__((ext_vector_type(4))) float floatx4;

// Round-to-nearest-even f32->bf16. NOTE (R5 failure): v_cvt_pk_bf16_f32 does
// NOT match RNE (absmax 4.9e-4 -> 7.8e-3); keep bit-manip RNE. Pack fuses the
// combine into one v_perm_b32 (bit-identical, fewer VALU ops).
__device__ __forceinline__ unsigned short f2b(float f) {
  unsigned int v;
  __builtin_memcpy(&v, &f, 4);
  unsigned int r = (v + 0x7FFFu + ((v >> 16) & 1u)) >> 16;
  return (unsigned short)r;
}

// pack two fp32 -> bf16x2 (low = a, high = b), RNE, == (f2b(b)<<16)|f2b(a).
__device__ __forceinline__ unsigned int f2b_pk(float a, float b) {
  unsigned int ua, ub;
  __builtin_memcpy(&ua, &a, 4);
  __builtin_memcpy(&ub, &b, 4);
  ua = ua + 0x7FFFu + ((ua >> 16) & 1u);
  ub = ub + 0x7FFFu + ((ub >> 16) & 1u);
#if __has_builtin(__builtin_amdgcn_perm)
  // bytes: dst = { ub.b3, ub.b2, ua.b3, ua.b2 }
  return __builtin_amdgcn_perm(ub, ua, 0x07060302u);
#else
  return (ub & 0xFFFF0000u) | (ua >> 16);
#endif
}

__device__ __forceinline__ float fast_exp2(float x) {
#if __has_builtin(__builtin_amdgcn_exp2f)
  return __builtin_amdgcn_exp2f(x);
#else
  return __builtin_exp2f(x);
#endif
}

__device__ __forceinline__ void async_copy16(const void* g, void* l) {
  __builtin_amdgcn_global_load_lds(
      (const __attribute__((address_space(1))) unsigned int*)g,
      (__attribute__((address_space(3))) unsigned int*)l, 16, 0, 0);
}

// 0.125 (1/sqrt(dk)) * log2(e): folded into Q so attention uses exp2 directly.
#define QSCALE 0.18033688011112042f

// One launch converts x (1M float4 groups) + 4 weight matrices (256K groups each).
__global__ __launch_bounds__(256) void cvt_all_kernel(
    const float* __restrict__ x,
    const float* __restrict__ w0, const float* __restrict__ w1,
    const float* __restrict__ w2, const float* __restrict__ w3,
    unsigned short* __restrict__ xb,
    unsigned short* __restrict__ d0, unsigned short* __restrict__ d1,
    unsigned short* __restrict__ d2, unsigned short* __restrict__ d3)
{
  int gid = blockIdx.x * 256 + threadIdx.x;
  const float* src;
  unsigned short* dst;
  size_t off;
  if (gid < (1 << 20)) {
    src = x; dst = xb; off = gid;
  } else {
    int g = gid - (1 << 20);
    int w = g >> 18;
    off = g & 0x3FFFF;
    src = (w == 0) ? w0 : (w == 1) ? w1 : (w == 2) ? w2 : w3;
    dst = (w == 0) ? d0 : (w == 1) ? d1 : (w == 2) ? d2 : d3;
  }
  floatx4 v = *(const floatx4*)(src + off * 4);
  unsigned int lo = f2b_pk(v[0], v[1]), hi = f2b_pk(v[2], v[3]);
  unsigned long long r = ((unsigned long long)hi << 32) | lo;
  *(unsigned long long*)(dst + off * 4) = r;
}

// QKV GEMM: 128x128 tile, BK=32 (R8 measured-best), now with minimum
// 2-phase double-buffer: single barrier/iter; stage(t+1) issued right after
// the barrier and drained by the NEXT barrier (a full 16-MFMA compute later).
// Old structure was stage -> immediate vmcnt(0) drain -> compute: exposed
// full load latency every K-iter. Bytes per drain window unchanged (the R1
// BK=64 failure mode doubled them). LDS 32KB; grid-limited 3 blocks/CU.
// Swizzle unchanged: slot c holds chunk (c&3)^((c>>3)&3); reads use
// quad^((col>>1)&3). z=0: Q (pre-scaled), z=1: K, z=2: V as VT[bh][d][t].
__global__ __launch_bounds__(256) void gemm_qkv_kernel(
    const unsigned short* __restrict__ A,
    const unsigned short* __restrict__ W0, const unsigned short* __restrict__ W1,
    const unsigned short* __restrict__ W2,
    const float* __restrict__ bias0, const float* __restrict__ bias1,
    const float* __restrict__ bias2,
    unsigned short* __restrict__ Qo, unsigned short* __restrict__ Ko,
    unsigned short* __restrict__ VTo)
{
  const int z = blockIdx.z;
  const unsigned short* W  = (z == 0) ? W0 : (z == 1) ? W1 : W2;
  const float* bias        = (z == 0) ? bias0 : (z == 1) ? bias1 : bias2;

  __shared__ alignas(16) unsigned short sA[2][128 * 32];
  __shared__ alignas(16) unsigned short sB[2][128 * 32];

  const int tid  = threadIdx.x;
  const int lane = tid & 63;
  const int wave = tid >> 6;
  const int col  = lane & 15;
  const int quad = lane >> 4;
  const int wm   = (wave >> 1) * 64;
  const int wn   = (wave & 1) * 64;
  const int m0   = blockIdx.y * 128;
  const int n0   = blockIdx.x * 128;
  const int swz8 = (quad ^ ((col >> 1) & 3)) * 8;

  // Per-thread staging bases: rows tid>>2 and tid>>2+64, fixed swizzled chunk.
  const int scs = ((tid & 3) ^ ((tid >> 3) & 3)) * 8;
  const unsigned short* Abase = A + (size_t)(m0 + (tid >> 2)) * 1024 + scs;
  const unsigned short* Wbase = W + (size_t)(n0 + (tid >> 2)) * 1024 + scs;

  floatx4 acc[4][4];
#pragma unroll
  for (int i = 0; i < 4; ++i)
#pragma unroll
    for (int j = 0; j < 4; ++j) acc[i][j] = (floatx4){0.f, 0.f, 0.f, 0.f};

  // Prologue: stage k0=0 into buffer 0.
  async_copy16(Abase, sA[0] + tid * 8);
  async_copy16(Abase + 65536, sA[0] + (256 + tid) * 8);
  async_copy16(Wbase, sB[0] + tid * 8);
  async_copy16(Wbase + 65536, sB[0] + (256 + tid) * 8);

  for (int k0 = 0; k0 < 1024; k0 += 32) {
    const int cur = (k0 >> 5) & 1;
    // ONE barrier: drains staging into buf cur (vmcnt(0) from __syncthreads)
    // and ensures reads of buf cur^1 from last iter are done.
    __syncthreads();
    if (k0 + 32 < 1024) {
      const int nxt = cur ^ 1;
      async_copy16(Abase + k0 + 32, sA[nxt] + tid * 8);
      async_copy16(Abase + 65536 + k0 + 32, sA[nxt] + (256 + tid) * 8);
      async_copy16(Wbase + k0 + 32, sB[nxt] + tid * 8);
      async_copy16(Wbase + 65536 + k0 + 32, sB[nxt] + (256 + tid) * 8);
    }
    short8 af[4], bf[4];
#pragma unroll
    for (int mi = 0; mi < 4; ++mi)
      af[mi] = *(const short8*)(sA[cur] + (wm + mi * 16 + col) * 32 + swz8);
#pragma unroll
    for (int ni = 0; ni < 4; ++ni)
      bf[ni] = *(const short8*)(sB[cur] + (wn + ni * 16 + col) * 32 + swz8);
#pragma unroll
    for (int mi = 0; mi < 4; ++mi)
#pragma unroll
      for (int ni = 0; ni < 4; ++ni)
        acc[mi][ni] = __builtin_amdgcn_mfma_f32_16x16x32_bf16(af[mi], bf[ni], acc[mi][ni], 0, 0, 0);
  }

#pragma unroll
  for (int ni = 0; ni < 4; ++ni) {
    int n = n0 + wn + ni * 16 + col;
    float bv = bias[n];
#pragma unroll
    for (int mi = 0; mi < 4; ++mi) {
      int mbase = m0 + wm + mi * 16 + quad * 4;
      if (z == 2) {
        // 4 consecutive t per lane: one packed 8B store.
        int d = n & 63, h = n >> 6;
        int bb = mbase >> 11, t = mbase & 2047;
        unsigned int lo = f2b_pk(acc[mi][ni][0] + bv, acc[mi][ni][1] + bv);
        unsigned int hi = f2b_pk(acc[mi][ni][2] + bv, acc[mi][ni][3] + bv);
        unsigned long long wv = ((unsigned long long)hi << 32) | lo;
        *(unsigned long long*)(VTo + (((size_t)bb * 16 + h) * 64 + d) * 2048 + t) = wv;
      } else {
#pragma unroll
        for (int r = 0; r < 4; ++r) {
          int m = mbase + r;
          float val = acc[mi][ni][r] + bv;
          if (z == 0) Qo[(size_t)m * 1024 + n] = f2b(val * QSCALE);
          else        Ko[(size_t)m * 1024 + n] = f2b(val);
        }
      }
    }
  }
}

// Out-proj GEMM: 128(M)x64(N) tile, BK=32, same 2-phase dbuf; fp32 output.
__global__ __launch_bounds__(256) void gemm_out_kernel(
    const unsigned short* __restrict__ A, const unsigned short* __restrict__ W,
    const float* __restrict__ bias, float* __restrict__ DF)
{
  __shared__ alignas(16) unsigned short sA[2][128 * 32];
  __shared__ alignas(16) unsigned short sB[2][64 * 32];

  const int tid  = threadIdx.x;
  const int lane = tid & 63;
  const int wave = tid >> 6;
  const int col  = lane & 15;
  const int quad = lane >> 4;
  const int wm   = (wave >> 1) * 64;
  const int wn   = (wave & 1) * 32;
  const int m0   = blockIdx.y * 128;
  const int n0   = blockIdx.x * 64;
  const int swz8 = (quad ^ ((col >> 1) & 3)) * 8;

  const int scs = ((tid & 3) ^ ((tid >> 3) & 3)) * 8;
  const unsigned short* Abase = A + (size_t)(m0 + (tid >> 2)) * 1024 + scs;
  const unsigned short* Wbase = W + (size_t)(n0 + (tid >> 2)) * 1024 + scs;

  floatx4 acc[4][2];
#pragma unroll
  for (int i = 0; i < 4; ++i)
#pragma unroll
    for (int j = 0; j < 2; ++j) acc[i][j] = (floatx4){0.f, 0.f, 0.f, 0.f};

  // Prologue: stage k0=0 into buffer 0.
  async_copy16(Abase, sA[0] + tid * 8);
  async_copy16(Abase + 65536, sA[0] + (256 + tid) * 8);
  async_copy16(Wbase, sB[0] + tid * 8);

  for (int k0 = 0; k0 < 1024; k0 += 32) {
    const int cur = (k0 >> 5) & 1;
    __syncthreads();
    if (k0 + 32 < 1024) {
      const int nxt = cur ^ 1;
      async_copy16(Abase + k0 + 32, sA[nxt] + tid * 8);
      async_copy16(Abase + 65536 + k0 + 32, sA[nxt] + (256 + tid) * 8);
      async_copy16(Wbase + k0 + 32, sB[nxt] + tid * 8);
    }
    short8 af[4], bf[2];
#pragma unroll
    for (int mi = 0; mi < 4; ++mi)
      af[mi] = *(const short8*)(sA[cur] + (wm + mi * 16 + col) * 32 + swz8);
#pragma unroll
    for (int ni = 0; ni < 2; ++ni)
      bf[ni] = *(const short8*)(sB[cur] + (wn + ni * 16 + col) * 32 + swz8);
#pragma unroll
    for (int mi = 0; mi < 4; ++mi)
#pragma unroll
      for (int ni = 0; ni < 2; ++ni)
        acc[mi][ni] = __builtin_amdgcn_mfma_f32_16x16x32_bf16(af[mi], bf[ni], acc[mi][ni], 0, 0, 0);
  }

#pragma unroll
  for (int ni = 0; ni < 2; ++ni) {
    int n = n0 + wn + ni * 16 + col;
    float bv = bias[n];
#pragma unroll
    for (int mi = 0; mi < 4; ++mi) {
      int mbase = m0 + wm + mi * 16 + quad * 4;
#pragma unroll
      for (int r = 0; r < 4; ++r)
        DF[(size_t)(mbase + r) * 1024 + n] = acc[mi][ni][r] + bv;
    }
  }
}

// Flash attention: same per-wave math as R6 (32 q-rows/wave, dual 16-row
// groups sharing every K/V fragment; K+V dbuf; single barrier/iter;
// wave-private sP; perm-pack; setprio) but re-partitioned to 1024 blocks x
// 128 threads (2 waves, 64 q-rows). Same 8 waves/CU; now 4 independent
// barrier-groups/CU instead of 2 -> cross-block pipe overlap (the 4300
// cy/CU-iter invariant had LDS~2550 + VALU~1720 + MFMA~1240 poorly
// overlapped; more independent pipelines raise overlap).
// Staging remapped for 128 threads: 4 chunks/thread (rows srow, srow+32 x
// halves 0,1); swizzle term invariant under +32 rows.
// LDS: 16K (K dbuf) + 16K (V dbuf) + 8K (sP) = 40960 B -> 4 blocks/CU.
__global__ __launch_bounds__(128, 2) void attention_kernel(
    const unsigned short* __restrict__ Q, const unsigned short* __restrict__ K,
    const unsigned short* __restrict__ VT, unsigned short* __restrict__ CTX)
{
  __shared__ alignas(16) unsigned short sK[2][4096];
  __shared__ alignas(16) unsigned short sV[2][4096];
  __shared__ alignas(16) unsigned short sP[2][32 * 64];

  // XCD-aware decode: 1024 blocks, xcd = flat&7 owns 4 consecutive bh
  // (4 x (K+V) = 2 MB in the 4 MB per-XCD L2). 32 q-chunks of 64 per bh.
  const int flat = blockIdx.x;
  const int idx  = flat >> 3;
  const int bh   = (flat & 7) * 4 + (idx >> 5);
  const int q0   = (idx & 31) * 64;
  const int b = bh >> 4, h = bh & 15;

  const int tid  = threadIdx.x;
  const int lane = tid & 63;
  const int wave = tid >> 6;          // 0..1
  const int col  = lane & 15;
  const int quad = lane >> 4;
  const int c7   = col & 7;
  const int swz8 = (quad ^ ((col >> 1) & 3)) * 8;

  const int srow = tid >> 2;                            // 0..31
  const int sko  = ((tid & 3) ^ ((tid >> 3) & 3)) * 8;  // swizzled source chunk

  const unsigned short* kbase = K + ((size_t)b * 2048 + srow) * 1024 + h * 64;
  const unsigned short* vbase = VT + ((size_t)bh * 64 + srow) * 2048;

  // Q fragments direct global->reg for BOTH 16-row groups (A: rows qw..qw+15,
  // B: rows qw+16..qw+31), qw = q0 + wave*32.
  short8 qfA[2], qfB[2];
  {
    const unsigned short* qp =
        Q + ((size_t)(b * 2048 + q0 + wave * 32 + col)) * 1024 + h * 64 + quad * 8;
    qfA[0] = *(const short8*)qp;
    qfA[1] = *(const short8*)(qp + 32);
    qfB[0] = *(const short8*)(qp + 16 * 1024);
    qfB[1] = *(const short8*)(qp + 16 * 1024 + 32);
  }

  // Staging: rows srow & srow+32, halves 0 & 1 (4 chunks/thread per tile).
  // LDS layout per tile: [half][row][4 chunks of 8 shorts] (c*8 linear).
#define STAGE_KV(ktv, buf)                                                     \
  do {                                                                         \
    const unsigned short* kp = kbase + (size_t)(ktv) * 1024 + sko;             \
    async_copy16(kp, sK[buf] + tid * 8);                                       \
    async_copy16(kp + 32 * 1024, sK[buf] + (128 + tid) * 8);                   \
    async_copy16(kp + 32, sK[buf] + (256 + tid) * 8);                          \
    async_copy16(kp + 32 * 1024 + 32, sK[buf] + (384 + tid) * 8);              \
    const unsigned short* vp = vbase + (ktv) + sko;                            \
    async_copy16(vp, sV[buf] + tid * 8);                                       \
    async_copy16(vp + 32 * 2048, sV[buf] + (128 + tid) * 8);                   \
    async_copy16(vp + 32, sV[buf] + (256 + tid) * 8);                          \
    async_copy16(vp + 32 * 2048 + 32, sV[buf] + (384 + tid) * 8);              \
  } while (0)

  // Prologue: stage tile 0 into buffer 0.
  STAGE_KV(0, 0);

  floatx4 OA[4], OB[4];
#pragma unroll
  for (int f = 0; f < 4; ++f) {
    OA[f] = (floatx4){0.f, 0.f, 0.f, 0.f};
    OB[f] = (floatx4){0.f, 0.f, 0.f, 0.f};
  }
  float laccA = 0.f, laccB = 0.f;  // per-lane partial sums for q-row = col

  unsigned short* myP = &sP[wave][0];

#pragma unroll 2
  for (int kt = 0; kt < 2048; kt += 64) {
    const int cur = (kt >> 6) & 1;
    const unsigned short* sKc = sK[cur];
    const unsigned short* sVc = sV[cur];
    // The ONE barrier: drains K(t),V(t) staging (vmcnt(0) from __syncthreads)
    // and ensures both waves finished reading the cur^1 buffers last iter.
    __syncthreads();
    // Issue next tile into the other buffers; drained a full iter from now.
    if (kt + 64 < 2048) {
      STAGE_KV(kt + 64, cur ^ 1);
    }

    // S^T blocks: rows k = f*16+quad*4+r, col q. One kf pair feeds BOTH
    // q-groups (the amortization).
    floatx4 STA[4], STB[4];
    __builtin_amdgcn_s_setprio(1);
#pragma unroll
    for (int f = 0; f < 4; ++f) {
      short8 kf0 = *(const short8*)(sKc + (f * 16 + col) * 32 + swz8);
      short8 kf1 = *(const short8*)(sKc + 2048 + (f * 16 + col) * 32 + swz8);
      STA[f] = (floatx4){0.f, 0.f, 0.f, 0.f};
      STA[f] = __builtin_amdgcn_mfma_f32_16x16x32_bf16(kf0, qfA[0], STA[f], 0, 0, 0);
      STA[f] = __builtin_amdgcn_mfma_f32_16x16x32_bf16(kf1, qfA[1], STA[f], 0, 0, 0);
      STB[f] = (floatx4){0.f, 0.f, 0.f, 0.f};
      STB[f] = __builtin_amdgcn_mfma_f32_16x16x32_bf16(kf0, qfB[0], STB[f], 0, 0, 0);
      STB[f] = __builtin_amdgcn_mfma_f32_16x16x32_bf16(kf1, qfB[1], STB[f], 0, 0, 0);
    }
    __builtin_amdgcn_s_setprio(0);

    // softmax numerators. P rows: group A -> col, group B -> 16+col.
    // (16+col)&7 == col&7, so the same XOR swizzle constant works.
#pragma unroll
    for (int f = 0; f < 4; ++f) {
      float a0 = fast_exp2(STA[f][0]);
      float a1 = fast_exp2(STA[f][1]);
      float a2 = fast_exp2(STA[f][2]);
      float a3 = fast_exp2(STA[f][3]);
      laccA += (a0 + a1) + (a2 + a3);
      unsigned long long wA =
          ((unsigned long long)f2b_pk(a2, a3) << 32) | f2b_pk(a0, a1);
      *(unsigned long long*)(myP + col * 64 +
                             (((f * 2 + (quad >> 1)) ^ c7) * 8) + (quad & 1) * 4) = wA;
      float b0 = fast_exp2(STB[f][0]);
      float b1 = fast_exp2(STB[f][1]);
      float b2 = fast_exp2(STB[f][2]);
      float b3 = fast_exp2(STB[f][3]);
      laccB += (b0 + b1) + (b2 + b3);
      unsigned long long wB =
          ((unsigned long long)f2b_pk(b2, b3) << 32) | f2b_pk(b0, b1);
      *(unsigned long long*)(myP + (16 + col) * 64 +
                             (((f * 2 + (quad >> 1)) ^ c7) * 8) + (quad & 1) * 4) = wB;
    }

    // wave-private sP: lgkmcnt orders write->read, no barrier needed.
    short8 pfA0 = *(const short8*)(myP + col * 64 + ((quad ^ c7) * 8));
    short8 pfA1 = *(const short8*)(myP + col * 64 + (((quad + 4) ^ c7) * 8));
    short8 pfB0 = *(const short8*)(myP + (16 + col) * 64 + ((quad ^ c7) * 8));
    short8 pfB1 = *(const short8*)(myP + (16 + col) * 64 + (((quad + 4) ^ c7) * 8));
    __builtin_amdgcn_s_setprio(1);
#pragma unroll
    for (int f = 0; f < 4; ++f) {
      short8 vf0 = *(const short8*)(sVc + (f * 16 + col) * 32 + swz8);
      short8 vf1 = *(const short8*)(sVc + 2048 + (f * 16 + col) * 32 + swz8);
      OA[f] = __builtin_amdgcn_mfma_f32_16x16x32_bf16(pfA0, vf0, OA[f], 0, 0, 0);
      OA[f] = __builtin_amdgcn_mfma_f32_16x16x32_bf16(pfA1, vf1, OA[f], 0, 0, 0);
      OB[f] = __builtin_amdgcn_mfma_f32_16x16x32_bf16(pfB0, vf0, OB[f], 0, 0, 0);
      OB[f] = __builtin_amdgcn_mfma_f32_16x16x32_bf16(pfB1, vf1, OB[f], 0, 0, 0);
    }
    __builtin_amdgcn_s_setprio(0);
  }

  // lacc holds partial sum for q=col over this quad's k slices; sum quads.
  laccA += __shfl_xor(laccA, 16, 64);
  laccA += __shfl_xor(laccA, 32, 64);
  laccB += __shfl_xor(laccB, 16, 64);
  laccB += __shfl_xor(laccB, 32, 64);
  // row sums for this lane's output rows q = quad*4+r
  float invA[4], invB[4];
#pragma unroll
  for (int r = 0; r < 4; ++r) {
    invA[r] = 1.f / __shfl(laccA, quad * 4 + r, 16);
    invB[r] = 1.f / __shfl(laccB, quad * 4 + r, 16);
  }

#pragma unroll
  for (int f = 0; f < 4; ++f) {
#pragma unroll
    for (int r = 0; r < 4; ++r) {
      int qA = q0 + wave * 32 + quad * 4 + r;
      int d = f * 16 + col;
      CTX[(size_t)(b * 2048 + qA) * 1024 + h * 64 + d] = f2b(OA[f][r] * invA[r]);
      CTX[(size_t)(b * 2048 + qA + 16) * 1024 + h * 64 + d] = f2b(OB[f][r] * invB[r]);
    }
  }
}

extern "C" void kernel_launch(void* const* d_in, const int* in_sizes, int n_in,
                              void* d_out, int out_size, void* d_ws, size_t ws_size,
                              hipStream_t stream) {
  const float* x   = (const float*)d_in[0];
  const float* W_q = (const float*)d_in[1];
  const float* b_q = (const float*)d_in[2];
  const float* W_k = (const float*)d_in[3];
  const float* b_k = (const float*)d_in[4];
  const float* W_v = (const float*)d_in[5];
  const float* b_v = (const float*)d_in[6];
  const float* W_o = (const float*)d_in[7];
  const float* b_o = (const float*)d_in[8];
  float* out = (float*)d_out;

  const size_t NX = (size_t)4096 * 1024;
  const size_t NW = (size_t)1024 * 1024;

  unsigned short* p   = (unsigned short*)d_ws;
  unsigned short* xb  = p;  p += NX;
  unsigned short* Wqb = p;  p += NW;
  unsigned short* Wkb = p;  p += NW;
  unsigned short* Wvb = p;  p += NW;
  unsigned short* Wob = p;  p += NW;
  unsigned short* Q   = p;  p += NX;
  unsigned short* Kb  = p;  p += NX;
  unsigned short* VT  = p;  p += NX;  // [32][64][2048]
  unsigned short* CTX = p;  p += NX;

  cvt_all_kernel<<<dim3(8192), dim3(256), 0, stream>>>(
      x, W_q, W_k, W_v, W_o, xb, Wqb, Wkb, Wvb, Wob);
  gemm_qkv_kernel<<<dim3(8, 32, 3), dim3(256), 0, stream>>>(
      xb, Wqb, Wkb, Wvb, b_q, b_k, b_v, Q, Kb, VT);
  attention_kernel<<<dim3(1024), dim3(128), 0, stream>>>(Q, Kb, VT, CTX);
  gemm_out_kernel<<<dim3(16, 32), dim3(256), 0, stream>>>(CTX, Wob, b_o, out);
}

// Round 10
// 190.216 us; speedup vs baseline: 1.0654x; 1.0654x over previous
//
#include <hip/hip_runtime.h>
#include <hip/hip_bf16.h>

typedef __attribute__((ext_vector_type(8))) short short8;
typedef __attribute__((ext_vector_type(4))) short short4v;
typedef __attribute__((ext_vector_type(4))) float floatx4;

// Round-to-nearest-even f32->bf16. NOTE (R5 failure): v_cvt_pk_bf16_f32 does
// NOT match RNE (absmax 4.9e-4 -> 7.8e-3); keep bit-manip RNE. Pack fuses the
// combine into one v_perm_b32 (bit-identical, fewer VALU ops).
__device__ __forceinline__ unsigned short f2b(float f) {
  unsigned int v;
  __builtin_memcpy(&v, &f, 4);
  unsigned int r = (v + 0x7FFFu + ((v >> 16) & 1u)) >> 16;
  return (unsigned short)r;
}

// pack two fp32 -> bf16x2 (low = a, high = b), RNE, == (f2b(b)<<16)|f2b(a).
__device__ __forceinline__ unsigned int f2b_pk(float a, float b) {
  unsigned int ua, ub;
  __builtin_memcpy(&ua, &a, 4);
  __builtin_memcpy(&ub, &b, 4);
  ua = ua + 0x7FFFu + ((ua >> 16) & 1u);
  ub = ub + 0x7FFFu + ((ub >> 16) & 1u);
#if __has_builtin(__builtin_amdgcn_perm)
  // bytes: dst = { ub.b3, ub.b2, ua.b3, ua.b2 }
  return __builtin_amdgcn_perm(ub, ua, 0x07060302u);
#else
  return (ub & 0xFFFF0000u) | (ua >> 16);
#endif
}

__device__ __forceinline__ float fast_exp2(float x) {
#if __has_builtin(__builtin_amdgcn_exp2f)
  return __builtin_amdgcn_exp2f(x);
#else
  return __builtin_exp2f(x);
#endif
}

__device__ __forceinline__ void async_copy16(const void* g, void* l) {
  __builtin_amdgcn_global_load_lds(
      (const __attribute__((address_space(1))) unsigned int*)g,
      (__attribute__((address_space(3))) unsigned int*)l, 16, 0, 0);
}

// 0.125 (1/sqrt(dk)) * log2(e): folded into Q so attention uses exp2 directly.
#define QSCALE 0.18033688011112042f

// One launch converts x (1M float4 groups) + 4 weight matrices (256K groups each).
__global__ __launch_bounds__(256) void cvt_all_kernel(
    const float* __restrict__ x,
    const float* __restrict__ w0, const float* __restrict__ w1,
    const float* __restrict__ w2, const float* __restrict__ w3,
    unsigned short* __restrict__ xb,
    unsigned short* __restrict__ d0, unsigned short* __restrict__ d1,
    unsigned short* __restrict__ d2, unsigned short* __restrict__ d3)
{
  int gid = blockIdx.x * 256 + threadIdx.x;
  const float* src;
  unsigned short* dst;
  size_t off;
  if (gid < (1 << 20)) {
    src = x; dst = xb; off = gid;
  } else {
    int g = gid - (1 << 20);
    int w = g >> 18;
    off = g & 0x3FFFF;
    src = (w == 0) ? w0 : (w == 1) ? w1 : (w == 2) ? w2 : w3;
    dst = (w == 0) ? d0 : (w == 1) ? d1 : (w == 2) ? d2 : d3;
  }
  floatx4 v = *(const floatx4*)(src + off * 4);
  unsigned int lo = f2b_pk(v[0], v[1]), hi = f2b_pk(v[2], v[3]);
  unsigned long long r = ((unsigned long long)hi << 32) | lo;
  *(unsigned long long*)(dst + off * 4) = r;
}

// QKV GEMM: C = A @ W^T + bias, 128x128 tile, BK=32. MEASURED-BEST config
// (R8 ledger: BK=32 0-phase beats BK=64 by ~15us total and beats 2-phase
// dbuf by ~6us — __syncthreads drains vmcnt(0) anyway, implicit 3-block/CU
// overlap already hides the latency; explicit dbuf only added overhead).
// XOR chunk swizzle: c'=(c&3)^((c>>3)&3); reads use quad^((col>>1)&3)
// (row-bases multiple of 16 vanish mod 4). 8-way -> 2-way.
// z=0: Q (pre-scaled by QSCALE), z=1: K, z=2: V written as VT[bh][d][t].
__global__ __launch_bounds__(256) void gemm_qkv_kernel(
    const unsigned short* __restrict__ A,
    const unsigned short* __restrict__ W0, const unsigned short* __restrict__ W1,
    const unsigned short* __restrict__ W2,
    const float* __restrict__ bias0, const float* __restrict__ bias1,
    const float* __restrict__ bias2,
    unsigned short* __restrict__ Qo, unsigned short* __restrict__ Ko,
    unsigned short* __restrict__ VTo)
{
  const int z = blockIdx.z;
  const unsigned short* W  = (z == 0) ? W0 : (z == 1) ? W1 : W2;
  const float* bias        = (z == 0) ? bias0 : (z == 1) ? bias1 : bias2;

  __shared__ alignas(16) unsigned short sA[128 * 32];
  __shared__ alignas(16) unsigned short sB[128 * 32];

  const int tid  = threadIdx.x;
  const int lane = tid & 63;
  const int wave = tid >> 6;
  const int col  = lane & 15;
  const int quad = lane >> 4;
  const int wm   = (wave >> 1) * 64;
  const int wn   = (wave & 1) * 64;
  const int m0   = blockIdx.y * 128;
  const int n0   = blockIdx.x * 128;
  const int swz8 = (quad ^ ((col >> 1) & 3)) * 8;

  floatx4 acc[4][4];
#pragma unroll
  for (int i = 0; i < 4; ++i)
#pragma unroll
    for (int j = 0; j < 4; ++j) acc[i][j] = (floatx4){0.f, 0.f, 0.f, 0.f};

  for (int k0 = 0; k0 < 1024; k0 += 32) {
    __syncthreads();
#pragma unroll
    for (int i = 0; i < 2; ++i) {
      int c   = i * 256 + tid;
      int row = c >> 2;
      int cs  = (c & 3) ^ ((c >> 3) & 3);  // swizzled source chunk
      int ko  = cs * 8;
      async_copy16(A + (size_t)(m0 + row) * 1024 + k0 + ko, sA + c * 8);
      async_copy16(W + (size_t)(n0 + row) * 1024 + k0 + ko, sB + c * 8);
    }
    __syncthreads();
    short8 af[4], bf[4];
#pragma unroll
    for (int mi = 0; mi < 4; ++mi)
      af[mi] = *(const short8*)(sA + (wm + mi * 16 + col) * 32 + swz8);
#pragma unroll
    for (int ni = 0; ni < 4; ++ni)
      bf[ni] = *(const short8*)(sB + (wn + ni * 16 + col) * 32 + swz8);
#pragma unroll
    for (int mi = 0; mi < 4; ++mi)
#pragma unroll
      for (int ni = 0; ni < 4; ++ni)
        acc[mi][ni] = __builtin_amdgcn_mfma_f32_16x16x32_bf16(af[mi], bf[ni], acc[mi][ni], 0, 0, 0);
  }

#pragma unroll
  for (int ni = 0; ni < 4; ++ni) {
    int n = n0 + wn + ni * 16 + col;
    float bv = bias[n];
#pragma unroll
    for (int mi = 0; mi < 4; ++mi) {
      int mbase = m0 + wm + mi * 16 + quad * 4;
      if (z == 2) {
        // 4 consecutive t per lane: one packed 8B store.
        int d = n & 63, h = n >> 6;
        int bb = mbase >> 11, t = mbase & 2047;
        unsigned int lo = f2b_pk(acc[mi][ni][0] + bv, acc[mi][ni][1] + bv);
        unsigned int hi = f2b_pk(acc[mi][ni][2] + bv, acc[mi][ni][3] + bv);
        unsigned long long wv = ((unsigned long long)hi << 32) | lo;
        *(unsigned long long*)(VTo + (((size_t)bb * 16 + h) * 64 + d) * 2048 + t) = wv;
      } else {
#pragma unroll
        for (int r = 0; r < 4; ++r) {
          int m = mbase + r;
          float val = acc[mi][ni][r] + bv;
          if (z == 0) Qo[(size_t)m * 1024 + n] = f2b(val * QSCALE);
          else        Ko[(size_t)m * 1024 + n] = f2b(val);
        }
      }
    }
  }
}

// Out-proj GEMM: 128(M)x64(N) tile, BK=32 + swizzle (R8 measured-best);
// fp32 output.
__global__ __launch_bounds__(256) void gemm_out_kernel(
    const unsigned short* __restrict__ A, const unsigned short* __restrict__ W,
    const float* __restrict__ bias, float* __restrict__ DF)
{
  __shared__ alignas(16) unsigned short sA[128 * 32];
  __shared__ alignas(16) unsigned short sB[64 * 32];

  const int tid  = threadIdx.x;
  const int lane = tid & 63;
  const int wave = tid >> 6;
  const int col  = lane & 15;
  const int quad = lane >> 4;
  const int wm   = (wave >> 1) * 64;
  const int wn   = (wave & 1) * 32;
  const int m0   = blockIdx.y * 128;
  const int n0   = blockIdx.x * 64;
  const int swz8 = (quad ^ ((col >> 1) & 3)) * 8;

  floatx4 acc[4][2];
#pragma unroll
  for (int i = 0; i < 4; ++i)
#pragma unroll
    for (int j = 0; j < 2; ++j) acc[i][j] = (floatx4){0.f, 0.f, 0.f, 0.f};

  for (int k0 = 0; k0 < 1024; k0 += 32) {
    __syncthreads();
#pragma unroll
    for (int i = 0; i < 2; ++i) {
      int c   = i * 256 + tid;
      int row = c >> 2;
      int cs  = (c & 3) ^ ((c >> 3) & 3);
      async_copy16(A + (size_t)(m0 + row) * 1024 + k0 + cs * 8, sA + c * 8);
    }
    {
      int row = tid >> 2;
      int cs  = (tid & 3) ^ ((tid >> 3) & 3);
      async_copy16(W + (size_t)(n0 + row) * 1024 + k0 + cs * 8, sB + tid * 8);
    }
    __syncthreads();
    short8 af[4], bf[2];
#pragma unroll
    for (int mi = 0; mi < 4; ++mi)
      af[mi] = *(const short8*)(sA + (wm + mi * 16 + col) * 32 + swz8);
#pragma unroll
    for (int ni = 0; ni < 2; ++ni)
      bf[ni] = *(const short8*)(sB + (wn + ni * 16 + col) * 32 + swz8);
#pragma unroll
    for (int mi = 0; mi < 4; ++mi)
#pragma unroll
      for (int ni = 0; ni < 2; ++ni)
        acc[mi][ni] = __builtin_amdgcn_mfma_f32_16x16x32_bf16(af[mi], bf[ni], acc[mi][ni], 0, 0, 0);
  }

#pragma unroll
  for (int ni = 0; ni < 2; ++ni) {
    int n = n0 + wn + ni * 16 + col;
    float bv = bias[n];
#pragma unroll
    for (int mi = 0; mi < 4; ++mi) {
      int mbase = m0 + wm + mi * 16 + quad * 4;
#pragma unroll
      for (int r = 0; r < 4; ++r)
        DF[(size_t)(mbase + r) * 1024 + n] = acc[mi][ni][r] + bv;
    }
  }
}

// Flash attention (R8 measured-best, unchanged): 512 blocks x 256 threads,
// 32 q-rows/wave (two 16-row MFMA groups sharing every K/V fragment read —
// the R4 amortization; R9 showed smaller blocks double staging traffic and
// regress), K+V double-buffered, single barrier/iter, wave-private sP,
// perm-pack RNE, setprio around MFMA clusters.
// LDS: 16K (K dbuf) + 16K (V dbuf) + 16K (sP) = 49152 B.
__global__ __launch_bounds__(256, 2) void attention_kernel(
    const unsigned short* __restrict__ Q, const unsigned short* __restrict__ K,
    const unsigned short* __restrict__ VT, unsigned short* __restrict__ CTX)
{
  __shared__ alignas(16) unsigned short sK[2][4096];
  __shared__ alignas(16) unsigned short sV[2][4096];
  __shared__ alignas(16) unsigned short sP[4][32 * 64];

  // XCD-aware decode: 512 blocks, xcd = flat&7 owns 4 consecutive bh
  // (4 x (K+V) = 2 MB in the 4 MB per-XCD L2). 16 q-chunks of 128 per bh.
  const int flat = blockIdx.x;
  const int idx  = flat >> 3;
  const int bh   = (flat & 7) * 4 + (idx >> 4);
  const int q0   = (idx & 15) * 128;
  const int b = bh >> 4, h = bh & 15;

  const int tid  = threadIdx.x;
  const int lane = tid & 63;
  const int wave = tid >> 6;
  const int col  = lane & 15;
  const int quad = lane >> 4;
  const int c7   = col & 7;
  const int swz8 = (quad ^ ((col >> 1) & 3)) * 8;

  const int srow = tid >> 2;                            // staging row within slab
  const int sko  = ((tid & 3) ^ ((tid >> 3) & 3)) * 8;  // swizzled source chunk

  const unsigned short* kbase = K + ((size_t)b * 2048 + srow) * 1024 + h * 64;
  const unsigned short* vbase = VT + ((size_t)bh * 64 + srow) * 2048;

  // Q fragments direct global->reg for BOTH 16-row groups (A: rows qw..qw+15,
  // B: rows qw+16..qw+31), qw = q0 + wave*32.
  short8 qfA[2], qfB[2];
  {
    const unsigned short* qp =
        Q + ((size_t)(b * 2048 + q0 + wave * 32 + col)) * 1024 + h * 64 + quad * 8;
    qfA[0] = *(const short8*)qp;
    qfA[1] = *(const short8*)(qp + 32);
    qfB[0] = *(const short8*)(qp + 16 * 1024);
    qfB[1] = *(const short8*)(qp + 16 * 1024 + 32);
  }

  // Prologue: stage tile 0 (K and V) into buffer 0.
#pragma unroll
  for (int i = 0; i < 2; ++i) {
    async_copy16(kbase + i * 32 + sko, sK[0] + (i * 256 + tid) * 8);
    async_copy16(vbase + i * 32 + sko, sV[0] + (i * 256 + tid) * 8);
  }

  floatx4 OA[4], OB[4];
#pragma unroll
  for (int f = 0; f < 4; ++f) {
    OA[f] = (floatx4){0.f, 0.f, 0.f, 0.f};
    OB[f] = (floatx4){0.f, 0.f, 0.f, 0.f};
  }
  float laccA = 0.f, laccB = 0.f;  // per-lane partial sums for q-row = col

  unsigned short* myP = &sP[wave][0];

#pragma unroll 2
  for (int kt = 0; kt < 2048; kt += 64) {
    const int cur = (kt >> 6) & 1;
    const unsigned short* sKc = sK[cur];
    const unsigned short* sVc = sV[cur];
    // The ONE barrier: drains K(t),V(t) staging (vmcnt(0) from __syncthreads)
    // and ensures all waves finished reading the cur^1 buffers last iter.
    __syncthreads();
    // Issue next tile into the other buffers; drained a full iter from now.
    if (kt + 64 < 2048) {
      const int nxt = cur ^ 1;
#pragma unroll
      for (int i = 0; i < 2; ++i) {
        async_copy16(kbase + (size_t)(kt + 64) * 1024 + i * 32 + sko,
                     sK[nxt] + (i * 256 + tid) * 8);
        async_copy16(vbase + (kt + 64) + i * 32 + sko,
                     sV[nxt] + (i * 256 + tid) * 8);
      }
    }

    // S^T blocks: rows k = f*16+quad*4+r, col q. One kf pair feeds BOTH
    // q-groups (the amortization).
    floatx4 STA[4], STB[4];
    __builtin_amdgcn_s_setprio(1);
#pragma unroll
    for (int f = 0; f < 4; ++f) {
      short8 kf0 = *(const short8*)(sKc + (f * 16 + col) * 32 + swz8);
      short8 kf1 = *(const short8*)(sKc + 2048 + (f * 16 + col) * 32 + swz8);
      STA[f] = (floatx4){0.f, 0.f, 0.f, 0.f};
      STA[f] = __builtin_amdgcn_mfma_f32_16x16x32_bf16(kf0, qfA[0], STA[f], 0, 0, 0);
      STA[f] = __builtin_amdgcn_mfma_f32_16x16x32_bf16(kf1, qfA[1], STA[f], 0, 0, 0);
      STB[f] = (floatx4){0.f, 0.f, 0.f, 0.f};
      STB[f] = __builtin_amdgcn_mfma_f32_16x16x32_bf16(kf0, qfB[0], STB[f], 0, 0, 0);
      STB[f] = __builtin_amdgcn_mfma_f32_16x16x32_bf16(kf1, qfB[1], STB[f], 0, 0, 0);
    }
    __builtin_amdgcn_s_setprio(0);

    // softmax numerators. P rows: group A -> col, group B -> 16+col.
    // (16+col)&7 == col&7, so the same XOR swizzle constant works.
#pragma unroll
    for (int f = 0; f < 4; ++f) {
      float a0 = fast_exp2(STA[f][0]);
      float a1 = fast_exp2(STA[f][1]);
      float a2 = fast_exp2(STA[f][2]);
      float a3 = fast_exp2(STA[f][3]);
      laccA += (a0 + a1) + (a2 + a3);
      unsigned long long wA =
          ((unsigned long long)f2b_pk(a2, a3) << 32) | f2b_pk(a0, a1);
      *(unsigned long long*)(myP + col * 64 +
                             (((f * 2 + (quad >> 1)) ^ c7) * 8) + (quad & 1) * 4) = wA;
      float b0 = fast_exp2(STB[f][0]);
      float b1 = fast_exp2(STB[f][1]);
      float b2 = fast_exp2(STB[f][2]);
      float b3 = fast_exp2(STB[f][3]);
      laccB += (b0 + b1) + (b2 + b3);
      unsigned long long wB =
          ((unsigned long long)f2b_pk(b2, b3) << 32) | f2b_pk(b0, b1);
      *(unsigned long long*)(myP + (16 + col) * 64 +
                             (((f * 2 + (quad >> 1)) ^ c7) * 8) + (quad & 1) * 4) = wB;
    }

    // wave-private sP: lgkmcnt orders write->read, no barrier needed.
    short8 pfA0 = *(const short8*)(myP + col * 64 + ((quad ^ c7) * 8));
    short8 pfA1 = *(const short8*)(myP + col * 64 + (((quad + 4) ^ c7) * 8));
    short8 pfB0 = *(const short8*)(myP + (16 + col) * 64 + ((quad ^ c7) * 8));
    short8 pfB1 = *(const short8*)(myP + (16 + col) * 64 + (((quad + 4) ^ c7) * 8));
    __builtin_amdgcn_s_setprio(1);
#pragma unroll
    for (int f = 0; f < 4; ++f) {
      short8 vf0 = *(const short8*)(sVc + (f * 16 + col) * 32 + swz8);
      short8 vf1 = *(const short8*)(sVc + 2048 + (f * 16 + col) * 32 + swz8);
      OA[f] = __builtin_amdgcn_mfma_f32_16x16x32_bf16(pfA0, vf0, OA[f], 0, 0, 0);
      OA[f] = __builtin_amdgcn_mfma_f32_16x16x32_bf16(pfA1, vf1, OA[f], 0, 0, 0);
      OB[f] = __builtin_amdgcn_mfma_f32_16x16x32_bf16(pfB0, vf0, OB[f], 0, 0, 0);
      OB[f] = __builtin_amdgcn_mfma_f32_16x16x32_bf16(pfB1, vf1, OB[f], 0, 0, 0);
    }
    __builtin_amdgcn_s_setprio(0);
  }

  // lacc holds partial sum for q=col over this quad's k slices; sum quads.
  laccA += __shfl_xor(laccA, 16, 64);
  laccA += __shfl_xor(laccA, 32, 64);
  laccB += __shfl_xor(laccB, 16, 64);
  laccB += __shfl_xor(laccB, 32, 64);
  // row sums for this lane's output rows q = quad*4+r
  float invA[4], invB[4];
#pragma unroll
  for (int r = 0; r < 4; ++r) {
    invA[r] = 1.f / __shfl(laccA, quad * 4 + r, 16);
    invB[r] = 1.f / __shfl(laccB, quad * 4 + r, 16);
  }

#pragma unroll
  for (int f = 0; f < 4; ++f) {
#pragma unroll
    for (int r = 0; r < 4; ++r) {
      int qA = q0 + wave * 32 + quad * 4 + r;
      int d = f * 16 + col;
      CTX[(size_t)(b * 2048 + qA) * 1024 + h * 64 + d] = f2b(OA[f][r] * invA[r]);
      CTX[(size_t)(b * 2048 + qA + 16) * 1024 + h * 64 + d] = f2b(OB[f][r] * invB[r]);
    }
  }
}

extern "C" void kernel_launch(void* const* d_in, const int* in_sizes, int n_in,
                              void* d_out, int out_size, void* d_ws, size_t ws_size,
                              hipStream_t stream) {
  const float* x   = (const float*)d_in[0];
  const float* W_q = (const float*)d_in[1];
  const float* b_q = (const float*)d_in[2];
  const float* W_k = (const float*)d_in[3];
  const float* b_k = (const float*)d_in[4];
  const float* W_v = (const float*)d_in[5];
  const float* b_v = (const float*)d_in[6];
  const float* W_o = (const float*)d_in[7];
  const float* b_o = (const float*)d_in[8];
  float* out = (float*)d_out;

  const size_t NX = (size_t)4096 * 1024;
  const size_t NW = (size_t)1024 * 1024;

  unsigned short* p   = (unsigned short*)d_ws;
  unsigned short* xb  = p;  p += NX;
  unsigned short* Wqb = p;  p += NW;
  unsigned short* Wkb = p;  p += NW;
  unsigned short* Wvb = p;  p += NW;
  unsigned short* Wob = p;  p += NW;
  unsigned short* Q   = p;  p += NX;
  unsigned short* Kb  = p;  p += NX;
  unsigned short* VT  = p;  p += NX;  // [32][64][2048]
  unsigned short* CTX = p;  p += NX;

  dim3 blk(256);
  cvt_all_kernel<<<dim3(8192), blk, 0, stream>>>(
      x, W_q, W_k, W_v, W_o, xb, Wqb, Wkb, Wvb, Wob);
  gemm_qkv_kernel<<<dim3(8, 32, 3), blk, 0, stream>>>(
      xb, Wqb, Wkb, Wvb, b_q, b_k, b_v, Q, Kb, VT);
  attention_kernel<<<dim3(512), blk, 0, stream>>>(Q, Kb, VT, CTX);
  gemm_out_kernel<<<dim3(16, 32), blk, 0, stream>>>(CTX, Wob, b_o, out);
}